// Round 2
// baseline (459.095 us; speedup 1.0000x reference)
//
#include <hip/hip_runtime.h>

// Wave-per-column cooperative search.
//
// Round-0 failure analysis: one-thread-per-column gives only 1024 waves
// (1 wave/SIMD, TLP=1) -> every search is round-trip-latency bound and no
// per-thread ILP trick fixes that. Here ONE WAVE serves ONE COLUMN:
//   R1: lane i probes row i*s1 (s1 = ntime/64); ballot+popcount -> 16-row
//       bucket. Probed rows are the SAME for all columns (16 MB) and the
//       XCD swizzle keeps contiguous columns on one XCD -> L2-resident.
//   R2: lanes 0..s1-1 probe the bucket; ballot+popcount -> exact lo;
//       times[lo-1], times[lo] recovered via __shfl from probe registers.
//   Epilogue: two values[] gathers, lane 0 stores.
// 65536 waves (64/SIMD of work) fully hide the 3 dependent rounds; cost is
// ~17 scattered 64B lines per column (~71 MB) + L2-resident R1.
//
// Counting semantics (lo = #{times <= tq}) exactly match the reference's
// sum((times - t) <= 0), including duplicate-knot behavior, because sorted
// input makes the two-level count exact.
__global__ void __launch_bounds__(256) bts_interp_wave(
        const float* __restrict__ times,
        const float* __restrict__ values,
        const float* __restrict__ t,
        float* __restrict__ out,
        int ntime, int nbatch, int s1, int cpx) {
    int lane = threadIdx.x & 63;
    int bid  = blockIdx.x;
    // XCD swizzle: 8 XCDs, contiguous column chunk per XCD so R1's 64 rows
    // (only this chunk's 64B segments, ~2 MB/XCD) stay L2-resident.
    if (cpx > 0) bid = (bid & 7) * cpx + (bid >> 3);
    int col = bid * 4 + (threadIdx.x >> 6);
    if (col >= nbatch) return;   // wave-uniform

    const long stride = nbatch;
    float tq = t[col];           // col wave-uniform -> scalar load

    // ---- Round 1: 64 probes at rows {0, s1, 2*s1, ...}.
    float v1 = times[(long)(lane * s1) * stride + col];
    unsigned long long m1 = __ballot(v1 <= tq);
    int c = __popcll(m1);        // sorted => probes 0..c-1 <= tq < probes c..63

    int lo;
    float t0 = 0.0f, t1 = 0.0f;
    if (c == 0) {
        lo = 0;                  // tq < times[0]; epilogue takes wrap branch
    } else {
        int base = (c - 1) * s1; // times[base] <= tq < times[c*s1] (virtual +inf)
        // ---- Round 2: lanes 0..s1-1 probe rows base..base+s1-1.
        // (lane 0 re-reads R1's lane c-1 address -> L1 hit, not new traffic)
        float v2 = 0.0f;
        if (lane < s1) v2 = times[(long)(base + lane) * stride + col];
        unsigned long long m2 = __ballot((lane < s1) && (v2 <= tq));
        int d = __popcll(m2);    // in [1, s1]
        lo = base + d;           // exact count of times <= tq
        t0 = __shfl(v2, d - 1);              // times[lo-1]
        if (d < s1)      t1 = __shfl(v2, d); // times[lo] from window
        else if (c < 64) t1 = __shfl(v1, c); // times[lo] = times[c*s1] from R1
        // else lo == ntime: t1 unused (wrap branch)
    }

    float res;
    if (lo > 0 && lo < ntime) {
        long p = (long)(lo - 1) * stride + col;
        float va = values[p];
        float vb = values[p + stride];
        res = va + (vb - va) / (t1 - t0) * (tq - t0);
    } else {
        // gi == 0 wrap: iv = ntime-1, isl = ntime-2 (torch negative-index wrap)
        long p = (long)(ntime - 2) * stride + col;
        float ta = times[p], tb = times[p + stride];
        float va = values[p], vb = values[p + stride];
        res = vb + (vb - va) / (tb - ta) * (tq - tb);
    }
    if (lane == 0) out[col] = res;
}

// Fallback for shapes the cooperative kernel doesn't cover: the verified
// per-thread upper-bound binary search (captures bracket times in-register).
__global__ void bts_interp_fallback(const float* __restrict__ times,
                                    const float* __restrict__ values,
                                    const float* __restrict__ t,
                                    float* __restrict__ out,
                                    int ntime, int nbatch) {
    int b = blockIdx.x * blockDim.x + threadIdx.x;
    if (b >= nbatch) return;

    float tq = t[b];
    int lo = 0, hi = ntime;
    float t0v = 0.0f, t1v = 0.0f;
    while (lo < hi) {
        int mid = (lo + hi) >> 1;
        float v = times[(long)mid * nbatch + b];
        if (v <= tq) { lo = mid + 1; t0v = v; }
        else         { hi = mid;     t1v = v; }
    }
    float res;
    if (lo > 0 && lo < ntime) {
        long base = (long)(lo - 1) * nbatch + b;
        float va = values[base];
        float vb = values[base + nbatch];
        res = va + (vb - va) / (t1v - t0v) * (tq - t0v);
    } else {
        long base = (long)(ntime - 2) * nbatch + b;
        float ta = times[base];
        float tb = times[base + nbatch];
        float va = values[base];
        float vb = values[base + nbatch];
        res = vb + (vb - va) / (tb - ta) * (tq - tb);
    }
    out[b] = res;
}

extern "C" void kernel_launch(void* const* d_in, const int* in_sizes, int n_in,
                              void* d_out, int out_size, void* d_ws, size_t ws_size,
                              hipStream_t stream) {
    const float* times  = (const float*)d_in[0];
    const float* values = (const float*)d_in[1];
    const float* t      = (const float*)d_in[2];
    float* out = (float*)d_out;

    int nbatch = in_sizes[2];
    int ntime  = in_sizes[0] / nbatch;

    if (ntime >= 64 && ntime % 64 == 0 && (ntime / 64) <= 64) {
        int s1 = ntime / 64;                      // 16 for ntime=1024
        int nblocks = (nbatch + 3) / 4;           // 4 waves (columns) per block
        int cpx = (nblocks % 8 == 0) ? (nblocks / 8) : 0;  // bijective swizzle only
        bts_interp_wave<<<nblocks, 256, 0, stream>>>(times, values, t, out,
                                                     ntime, nbatch, s1, cpx);
    } else {
        const int BLOCK = 256;
        int grid = (nbatch + BLOCK - 1) / BLOCK;
        bts_interp_fallback<<<grid, BLOCK, 0, stream>>>(times, values, t, out,
                                                        ntime, nbatch);
    }
}

// Round 3
// 407.668 us; speedup vs baseline: 1.1261x; 1.1261x over previous
//
#include <hip/hip_runtime.h>

// Stride-8 coalesced subsampled scan + 3-probe binary finish.
//
// Model from rounds 0-2 (kernel portion 85 / 103 / 137 us tracks scattered
// 64B-line count ~7 / ~21 / ~30 per column): random-line traffic runs at
// ~1.5-2 TB/s effective; coalesced rows run at ~6.3 TB/s. So move the shallow
// search levels into the coalesced regime: each thread streams rows
// 0,8,...,ntime-8 of its column (perfectly coalesced across the 64 lanes,
// fully independent loads -> ILP hides latency even at 1 wave/SIMD),
// counting subsampled knots <= tq and capturing the subsampled bracket
// branchlessly. That pins lo to a 7-row window: 3 dependent scattered probes
// finish the search, then the usual 2 values[] gathers.
// Scattered lines/col: 7 -> 5; dependent rounds: 10 -> 4; shallow levels
// (previously ~16 MB of cache-thrashed probe lines) become a 32 MB coalesced
// stream.
//
// Counting semantics: sorted column + subsampled count cs means rows
// 0..8(cs-1) are all <= tq, and row 8*cs (if present) is > tq, so the exact
// count lo lies in [8(cs-1)+1, 8*cs]; upper-bound binary search over that
// window is exact, duplicates included.
#define SUB 8

__global__ void __launch_bounds__(256) bts_scan_kernel(
        const float* __restrict__ times,
        const float* __restrict__ values,
        const float* __restrict__ t,
        float* __restrict__ out,
        int ntime, int nbatch) {
    int b = blockIdx.x * blockDim.x + threadIdx.x;
    if (b >= nbatch) return;

    const long stride = nbatch;
    float tq = t[b];

    // ---- Coalesced subsampled scan: rows 0, SUB, 2*SUB, ...
    int nsub = ntime / SUB;
    int cs = 0;
    float t0s = 0.0f;                 // last subsampled value <= tq
    float t1s = __builtin_inff();     // first subsampled value  > tq
    const float* p = times + b;
    const long rstep = (long)SUB * stride;
#pragma unroll 16
    for (int k = 0; k < nsub; ++k) {
        float v = p[(long)k * rstep];
        bool le = (v <= tq);
        cs += le ? 1 : 0;
        t0s = le ? v : t0s;           // sorted: last success is the max
        t1s = (!le && v < t1s) ? v : t1s;  // sorted: first failure is the min
    }

    // ---- 3-probe binary finish inside the 7-row window.
    int lo, hi;
    float t0v = t0s, t1v = t1s;
    if (cs == 0) {
        lo = 0; hi = 0;               // tq < times[0]: wrap branch below
    } else {
        lo = SUB * (cs - 1) + 1;      // rows 0..8(cs-1) known <= tq
        hi = SUB * cs;                // row 8cs known > tq (or == ntime)
    }
    while (lo < hi) {
        int mid = (lo + hi) >> 1;
        float v = times[(long)mid * stride + b];
        if (v <= tq) { lo = mid + 1; t0v = v; }
        else         { hi = mid;     t1v = v; }
    }
    // lo == count(times[:,b] <= tq); t0v = times[lo-1] (lo>0),
    // t1v = times[lo] (lo<ntime).

    float res;
    if (lo > 0 && lo < ntime) {
        long base = (long)(lo - 1) * stride + b;
        float va = values[base];
        float vb = values[base + stride];
        res = va + (vb - va) / (t1v - t0v) * (tq - t0v);
    } else {
        // gi == 0 (t below all knots, or >= all knots): iv = ntime-1,
        // isl = ntime-2 (torch negative-index wrap).
        long base = (long)(ntime - 2) * stride + b;
        float ta = times[base];
        float tb = times[base + stride];
        float va = values[base];
        float vb = values[base + stride];
        res = vb + (vb - va) / (tb - ta) * (tq - tb);
    }
    out[b] = res;
}

// Fallback for shapes with ntime % SUB != 0 (or tiny ntime): the verified
// per-thread upper-bound binary search.
__global__ void bts_interp_fallback(const float* __restrict__ times,
                                    const float* __restrict__ values,
                                    const float* __restrict__ t,
                                    float* __restrict__ out,
                                    int ntime, int nbatch) {
    int b = blockIdx.x * blockDim.x + threadIdx.x;
    if (b >= nbatch) return;

    float tq = t[b];
    int lo = 0, hi = ntime;
    float t0v = 0.0f, t1v = 0.0f;
    while (lo < hi) {
        int mid = (lo + hi) >> 1;
        float v = times[(long)mid * nbatch + b];
        if (v <= tq) { lo = mid + 1; t0v = v; }
        else         { hi = mid;     t1v = v; }
    }
    float res;
    if (lo > 0 && lo < ntime) {
        long base = (long)(lo - 1) * nbatch + b;
        float va = values[base];
        float vb = values[base + nbatch];
        res = va + (vb - va) / (t1v - t0v) * (tq - t0v);
    } else {
        long base = (long)(ntime - 2) * nbatch + b;
        float ta = times[base];
        float tb = times[base + nbatch];
        float va = values[base];
        float vb = values[base + nbatch];
        res = vb + (vb - va) / (tb - ta) * (tq - tb);
    }
    out[b] = res;
}

extern "C" void kernel_launch(void* const* d_in, const int* in_sizes, int n_in,
                              void* d_out, int out_size, void* d_ws, size_t ws_size,
                              hipStream_t stream) {
    const float* times  = (const float*)d_in[0];
    const float* values = (const float*)d_in[1];
    const float* t      = (const float*)d_in[2];
    float* out = (float*)d_out;

    int nbatch = in_sizes[2];
    int ntime  = in_sizes[0] / nbatch;

    const int BLOCK = 256;
    int grid = (nbatch + BLOCK - 1) / BLOCK;
    if (ntime >= 2 * SUB && ntime % SUB == 0) {
        bts_scan_kernel<<<grid, BLOCK, 0, stream>>>(times, values, t, out,
                                                    ntime, nbatch);
    } else {
        bts_interp_fallback<<<grid, BLOCK, 0, stream>>>(times, values, t, out,
                                                        ntime, nbatch);
    }
}